// Round 7
// baseline (497.444 us; speedup 1.0000x reference)
//
#include <hip/hip_runtime.h>

#define T_STEPS 512
#define IN_DIM 11
#define ROW_PAD 12                  // x row padded to 12 f16 (24 B, 8-B aligned)
#define H_DIM 16
#define ROW_F (T_STEPS * IN_DIM)    // 5632 floats per batch row
#define CHUNK_T 16                  // t-steps per x chunk
#define CHUNK_F (CHUNK_T * IN_DIM)  // 176 source floats per chunk
#define N_CHUNK (T_STEPS / CHUNK_T)
#define LOG2E 1.44269504088896340736f

typedef _Float16 v2h __attribute__((ext_vector_type(2)));
typedef _Float16 v4h __attribute__((ext_vector_type(4)));

// v_dot2_f32_f16: D = a.x*b.x + a.y*b.y + c (f16 products exact in f32).
__device__ __forceinline__ float fdot2(v2h a, v2h b, float c) {
    return __builtin_amdgcn_fdot2(a, b, c, false);
}
__device__ __forceinline__ v2h as_v2h(int v) { return __builtin_bit_cast(v2h, v); }

// DPP quad_perm broadcast within each group of 4 lanes.
template<int CTRL>
__device__ __forceinline__ float qperm(float v) {
    return __builtin_bit_cast(float,
        __builtin_amdgcn_update_dpp(0, __builtin_bit_cast(int, v),
                                    CTRL, 0xf, 0xf, true));
}

__device__ __forceinline__ float bcast_lane(float v, int l) {
    return __builtin_bit_cast(float,
        __builtin_amdgcn_readlane(__builtin_bit_cast(int, v), l));
}

// One wave per batch element; lane = 4*r + gate (i,f,g,o quads).
// ROUND 7: the h-state broadcast no longer touches LDS. Rounds 4-6 were
// latency-bound on two ds_write->ds_read round trips (~120+ cyc each) per
// step on the recurrence critical path. New path: cvt_pkrtz (f16 dup) ->
// DPP row_shl:4 (lane 8j sees h[2j+1]) -> half-merge -> 8x v_readlane.
// h pairs then live in SGPRs; fdot2 consumes them as its single legal SGPR
// operand. Zero DS ops on the h path; only the prefetchable x reads remain.
__global__ __launch_bounds__(256)
__attribute__((amdgpu_waves_per_eu(4, 4)))
void lstm2_head(
    const float* __restrict__ x,
    const float* __restrict__ Wih1, const float* __restrict__ Whh1,
    const float* __restrict__ bih1, const float* __restrict__ bhh1,
    const float* __restrict__ Wih2, const float* __restrict__ Whh2,
    const float* __restrict__ bih2, const float* __restrict__ bhh2,
    const float* __restrict__ Wd1, const float* __restrict__ bd1,
    const float* __restrict__ Wd2, const float* __restrict__ bd2,
    const float* __restrict__ Wd3, const float* __restrict__ bd3,
    float* __restrict__ out)
{
    __shared__ __align__(16) _Float16 xlds[4][2][216];  // [wave][buf][padded chunk]

    const int lane = threadIdx.x & 63;
    const int wid = __builtin_amdgcn_readfirstlane((int)(threadIdx.x >> 6));
    const int b = blockIdx.x * 4 + wid;

    const int r   = lane >> 2;          // hidden index 0..15
    const int gt  = lane & 3;           // 0:i 1:f 2:g(tanh) 3:o
    const int row = gt * H_DIM + r;     // row in packed 4H weights

    const bool is_t = (gt == 2);
    const float M   = is_t ? (-2.0f * LOG2E) : (-LOG2E);
    const float vAa = is_t ? 2.0f : 1.0f;
    const float vBc = is_t ? -1.0f : 0.0f;

    // ---- per-lane weights, M-scaled, packed f16 pairs (pinned VGPRs) ----
    v2h wi1h[6], wh1h[8], wi2h[8], wh2h[8];
    #pragma unroll
    for (int j = 0; j < 5; ++j)
        wi1h[j] = (v2h){(_Float16)(M * Wih1[row * IN_DIM + 2 * j]),
                        (_Float16)(M * Wih1[row * IN_DIM + 2 * j + 1])};
    wi1h[5] = (v2h){(_Float16)(M * Wih1[row * IN_DIM + 10]), (_Float16)0.0f};
    #pragma unroll
    for (int j = 0; j < 8; ++j) {
        wh1h[j] = (v2h){(_Float16)(M * Whh1[row * H_DIM + 2 * j]),
                        (_Float16)(M * Whh1[row * H_DIM + 2 * j + 1])};
        wi2h[j] = (v2h){(_Float16)(M * Wih2[row * H_DIM + 2 * j]),
                        (_Float16)(M * Wih2[row * H_DIM + 2 * j + 1])};
        wh2h[j] = (v2h){(_Float16)(M * Whh2[row * H_DIM + 2 * j]),
                        (_Float16)(M * Whh2[row * H_DIM + 2 * j + 1])};
    }
    const float bb1 = M * (bih1[row] + bhh1[row]);
    const float bb2 = M * (bih2[row] + bhh2[row]);
    #pragma unroll
    for (int j = 0; j < 6; ++j) asm volatile("" : "+v"(wi1h[j]));
    #pragma unroll
    for (int j = 0; j < 8; ++j) {
        asm volatile("" : "+v"(wh1h[j]));
        asm volatile("" : "+v"(wi2h[j]));
        asm volatile("" : "+v"(wh2h[j]));
    }

    const float* __restrict__ xb = x + (size_t)b * ROW_F;
    _Float16* const xl0 = &xlds[wid][0][0];
    _Float16* const xl1 = &xlds[wid][1][0];

    // zero x pad slots (per-wave LDS, same-wave ordering, no barrier needed)
    if (lane < 32) {
        const int buf = lane >> 4, rr = lane & 15;
        xlds[wid][buf][rr * ROW_PAD + IN_DIM] = (_Float16)0.0f;
    }

    // staging: source float f -> padded f16 slot (f/11)*12 + f%11
    const int f1i = lane, f2i = lane + 64, f3i = lane + 128;
    const int p1 = (f1i / IN_DIM) * ROW_PAD + (f1i % IN_DIM);
    const int p2 = (f2i / IN_DIM) * ROW_PAD + (f2i % IN_DIM);
    const int p3 = (f3i / IN_DIM) * ROW_PAD + (f3i % IN_DIM);

    // prologue: global-load chunk 0
    float gl0 = xb[f1i];
    float gl1 = xb[f2i];
    float gl2 = xb[min(f3i, ROW_F - 1)];

    float c1 = 0.f, c2 = 0.f, h2v = 0.f, ssum = 0.f;
    // h pairs as packed f16 in wave-uniform ints (SGPR-resident)
    int h1p[8], h2p[8];
    #pragma unroll
    for (int j = 0; j < 8; ++j) { h1p[j] = 0; h2p[j] = 0; }

    // pack quad-replicated h (f32) into per-8-lane f16 pairs, then SGPRs:
    // lane 4r+g holds h[r]; pkrtz dups f16 into both halves; row_shl:4 gives
    // lane 8j the value h[2j+1]; merge -> lane 8j holds [h2j | h2j+1].
    #define HPACK(HV, DST)                                                      \
        {                                                                       \
            const int lo_ = __builtin_bit_cast(int,                             \
                __builtin_amdgcn_cvt_pkrtz(HV, HV));                            \
            const int hi_ = __builtin_amdgcn_update_dpp(0, lo_, 0x104,          \
                                                        0xf, 0xf, true);        \
            const int pk_ = (lo_ & 0xFFFF) | (hi_ & (int)0xFFFF0000u);          \
            _Pragma("unroll")                                                   \
            for (int j = 0; j < 8; ++j)                                         \
                DST[j] = __builtin_amdgcn_readlane(pk_, 8 * j);                 \
        }

    for (int ck = 0; ck < N_CHUNK; ++ck) {
        _Float16* const xbuf = (ck & 1) ? xl1 : xl0;
        xbuf[p1] = (_Float16)gl0;
        xbuf[p2] = (_Float16)gl1;
        xbuf[p3] = (_Float16)gl2;
        if (ck + 1 < N_CHUNK) {
            const int base = (ck + 1) * CHUNK_F;
            gl0 = xb[base + f1i];
            gl1 = xb[base + f2i];
            gl2 = xb[min(base + f3i, ROW_F - 1)];
        }

        #pragma unroll
        for (int t2 = 0; t2 < CHUNK_T; ++t2) {
            const v4h* const xr4 = (const v4h*)(xbuf + t2 * ROW_PAD);

            // ---- layer-2 recurrent dot (h2p in SGPRs, split chains) ----
            float a2 = bb2, b2 = 0.f;
            #pragma unroll
            for (int j = 0; j < 4; ++j) {
                a2 = fdot2(wh2h[j],     as_v2h(h2p[j]),     a2);
                b2 = fdot2(wh2h[j + 4], as_v2h(h2p[j + 4]), b2);
            }

            // ---- layer-1 preact: x (3x ds_read_b64) + recurrent (SGPRs) ----
            const v4h x0 = xr4[0], x1 = xr4[1], x2 = xr4[2];
            float a1 = bb1, b1 = 0.f;
            a1 = fdot2(wi1h[0], __builtin_shufflevector(x0, x0, 0, 1), a1);
            b1 = fdot2(wi1h[1], __builtin_shufflevector(x0, x0, 2, 3), b1);
            a1 = fdot2(wi1h[2], __builtin_shufflevector(x1, x1, 0, 1), a1);
            b1 = fdot2(wi1h[3], __builtin_shufflevector(x1, x1, 2, 3), b1);
            a1 = fdot2(wi1h[4], __builtin_shufflevector(x2, x2, 0, 1), a1);
            b1 = fdot2(wi1h[5], __builtin_shufflevector(x2, x2, 2, 3), b1);
            #pragma unroll
            for (int j = 0; j < 4; ++j) {
                a1 = fdot2(wh1h[j],     as_v2h(h1p[j]),     a1);
                b1 = fdot2(wh1h[j + 4], as_v2h(h1p[j + 4]), b1);
            }

            // ---- layer 1 activation + cell (fp32) ----
            const float g1 = a1 + b1;
            const float act1 = __builtin_fmaf(vAa,
                __builtin_amdgcn_rcpf(1.0f + __builtin_amdgcn_exp2f(g1)), vBc);
            float h1v;
            {
                const float gi = qperm<0x00>(act1);
                const float gf = qperm<0x55>(act1);
                const float gg = qperm<0xAA>(act1);
                const float go = qperm<0xFF>(act1);
                c1 = __builtin_fmaf(gf, c1, gi * gg);
                const float tc = __builtin_fmaf(2.0f,
                    __builtin_amdgcn_rcpf(1.0f +
                        __builtin_amdgcn_exp2f(-2.0f * LOG2E * c1)), -1.0f);
                h1v = go * tc;                      // quad-replicated
            }
            HPACK(h1v, h1p)

            #pragma unroll
            for (int j = 0; j < 4; ++j) {
                a2 = fdot2(wi2h[j],     as_v2h(h1p[j]),     a2);
                b2 = fdot2(wi2h[j + 4], as_v2h(h1p[j + 4]), b2);
            }

            // ---- layer 2 activation + cell (fp32) ----
            const float g2 = a2 + b2;
            const float act2 = __builtin_fmaf(vAa,
                __builtin_amdgcn_rcpf(1.0f + __builtin_amdgcn_exp2f(g2)), vBc);
            {
                const float gi = qperm<0x00>(act2);
                const float gf = qperm<0x55>(act2);
                const float gg = qperm<0xAA>(act2);
                const float go = qperm<0xFF>(act2);
                c2 = __builtin_fmaf(gf, c2, gi * gg);
                const float tc = __builtin_fmaf(2.0f,
                    __builtin_amdgcn_rcpf(1.0f +
                        __builtin_amdgcn_exp2f(-2.0f * LOG2E * c2)), -1.0f);
                h2v = go * tc;                      // quad-replicated
            }
            HPACK(h2v, h2p)

            ssum += __builtin_amdgcn_exp2f(LOG2E * h2v);
        }
    }
    #undef HPACK

    // s[b,k] = exp(h2[T-1,k]) / sum_t exp(h2[t,k]); h2v replicated per quad.
    const float sv = __builtin_amdgcn_exp2f(LOG2E * h2v) / ssum;

    float ssb[H_DIM];
    #pragma unroll
    for (int k = 0; k < H_DIM; ++k) ssb[k] = bcast_lane(sv, 4 * k);

    // Dense head 16 -> 8 -> 8 -> 3 + softmax (one-time epilogue, fp32).
    const int r8 = lane & 7;
    float acc1 = bd1[r8];
    #pragma unroll
    for (int k = 0; k < H_DIM; ++k)
        acc1 = __builtin_fmaf(Wd1[r8 * H_DIM + k], ssb[k], acc1);

    float d1s[8];
    #pragma unroll
    for (int j = 0; j < 8; ++j) d1s[j] = bcast_lane(acc1, j);

    float acc2 = bd2[r8];
    #pragma unroll
    for (int k = 0; k < 8; ++k)
        acc2 = __builtin_fmaf(Wd2[r8 * 8 + k], d1s[k], acc2);

    float d2s[8];
    #pragma unroll
    for (int j = 0; j < 8; ++j) d2s[j] = bcast_lane(acc2, j);

    float lg = 0.f;
    if (lane < 3) {
        lg = bd3[lane];
        #pragma unroll
        for (int k = 0; k < 8; ++k)
            lg = __builtin_fmaf(Wd3[lane * 8 + k], d2s[k], lg);
    }
    const float l0 = bcast_lane(lg, 0);
    const float l1 = bcast_lane(lg, 1);
    const float l2 = bcast_lane(lg, 2);
    const float mx = fmaxf(l0, fmaxf(l1, l2));
    const float e0 = __builtin_amdgcn_exp2f(LOG2E * (l0 - mx));
    const float e1 = __builtin_amdgcn_exp2f(LOG2E * (l1 - mx));
    const float e2 = __builtin_amdgcn_exp2f(LOG2E * (l2 - mx));
    const float inv = 1.0f / (e0 + e1 + e2);
    if (lane < 3) {
        const float ev = (lane == 0) ? e0 : ((lane == 1) ? e1 : e2);
        out[b * 3 + lane] = ev * inv;
    }
}

extern "C" void kernel_launch(void* const* d_in, const int* in_sizes, int n_in,
                              void* d_out, int out_size, void* d_ws, size_t ws_size,
                              hipStream_t stream) {
    (void)in_sizes; (void)n_in; (void)out_size; (void)d_ws; (void)ws_size;
    const float* x    = (const float*)d_in[0];
    const float* Wih1 = (const float*)d_in[1];
    const float* Whh1 = (const float*)d_in[2];
    const float* bih1 = (const float*)d_in[3];
    const float* bhh1 = (const float*)d_in[4];
    const float* Wih2 = (const float*)d_in[5];
    const float* Whh2 = (const float*)d_in[6];
    const float* bih2 = (const float*)d_in[7];
    const float* bhh2 = (const float*)d_in[8];
    const float* Wd1  = (const float*)d_in[9];
    const float* bd1  = (const float*)d_in[10];
    const float* Wd2  = (const float*)d_in[11];
    const float* bd2  = (const float*)d_in[12];
    const float* Wd3  = (const float*)d_in[13];
    const float* bd3  = (const float*)d_in[14];

    lstm2_head<<<dim3(4096 / 4), dim3(256), 0, stream>>>(
        x, Wih1, Whh1, bih1, bhh1, Wih2, Whh2, bih2, bhh2,
        Wd1, bd1, Wd2, bd2, Wd3, bd3, (float*)d_out);
}